// Round 6
// baseline (483.591 us; speedup 1.0000x reference)
//
#include <hip/hip_runtime.h>

// ---------------------------------------------------------------------------
// SparseAttention v4: all-f16 MFMA pipeline.
// x @ Wqkv^T -> top-k(204/2048) masked softmax attn -> @ Wout^T
// b=2 n=2048 d=1024 h=16 dh=64, scale=1/32 (folded into Wqkv cast), k_top=204.
// attn: 16 queries/WG, 512 threads (8 waves). Dots tile f16 in LDS; top-k
// threshold via ballot-based binary search on f16 bit-keys (registers only,
// zero LDS atomics); PV split across wave pairs with f32 LDS-atomic combine.
// ---------------------------------------------------------------------------

using f16x8 = __attribute__((ext_vector_type(8))) _Float16;
using u16x8 = __attribute__((ext_vector_type(8))) unsigned short;
using f32x4 = __attribute__((ext_vector_type(4))) float;

#define MFMA16F(a, b, c) __builtin_amdgcn_mfma_f32_16x16x32_f16(a, b, c, 0, 0, 0)

__device__ __forceinline__ unsigned short f2h(float f) {
  return __builtin_bit_cast(unsigned short, (_Float16)f);
}
__device__ __forceinline__ float h2f(unsigned int u) {
  return (float)__builtin_bit_cast(_Float16, (unsigned short)u);
}
// monotone f16-bits -> u16 key (larger key == larger value)
__device__ __forceinline__ unsigned int key16(unsigned int u) {
  return (u & 0x8000u) ? (~u & 0xFFFFu) : (u | 0x8000u);
}
__device__ __forceinline__ unsigned int inv_key16(unsigned int k) {
  return (k & 0x8000u) ? (k & 0x7FFFu) : (~k & 0xFFFFu);
}
__device__ __forceinline__ float wred_sum(float v) {
#pragma unroll
  for (int off = 32; off > 0; off >>= 1) v += __shfl_xor(v, off);
  return v;
}

// ---------------- cast f32 -> f16 (x4), optional 1/32 scale for first scaleN4 ----
__global__ void cast_f32_f16(const float* __restrict__ s,
                             unsigned short* __restrict__ d, int n4, int scaleN4) {
  int i = blockIdx.x * blockDim.x + threadIdx.x;
  int stride = gridDim.x * blockDim.x;
  for (; i < n4; i += stride) {
    float4 v = ((const float4*)s)[i];
    float sc = (i < scaleN4) ? 0.03125f : 1.0f;
    ushort4 o;
    o.x = f2h(v.x * sc); o.y = f2h(v.y * sc); o.z = f2h(v.z * sc); o.w = f2h(v.w * sc);
    ((ushort4*)d)[i] = o;
  }
}

// ---------------- GEMM1: qkv[4096][3072] = x @ Wqkv^T (f16, coalesced) -------
__global__ __launch_bounds__(256, 2) void gemm_qkv(
    const unsigned short* __restrict__ A, const unsigned short* __restrict__ W,
    unsigned short* __restrict__ out) {
  const int K = 1024;
  __shared__ unsigned short As[128 * 32];
  __shared__ unsigned short Bs[128 * 32];
  int t = threadIdx.x;
  int m0 = blockIdx.y * 128, n0 = blockIdx.x * 128;
  int lane = t & 63, wave = t >> 6;
  int wm = wave >> 1, wn = wave & 1;
  int rs = t >> 2, cs = t & 3;
  int cl = cs ^ ((rs >> 1) & 3);
  const unsigned short* pa0 = A + (size_t)(m0 + rs) * K + cl * 8;
  const unsigned short* pa1 = A + (size_t)(m0 + rs + 64) * K + cl * 8;
  const unsigned short* pb0 = W + (size_t)(n0 + rs) * K + cl * 8;
  const unsigned short* pb1 = W + (size_t)(n0 + rs + 64) * K + cl * 8;
  u16x8 ra0 = *(const u16x8*)pa0;
  u16x8 ra1 = *(const u16x8*)pa1;
  u16x8 rb0 = *(const u16x8*)pb0;
  u16x8 rb1 = *(const u16x8*)pb1;
  f32x4 zz = {0.f, 0.f, 0.f, 0.f};
  f32x4 acc[4][4];
#pragma unroll
  for (int i = 0; i < 4; ++i)
#pragma unroll
    for (int j = 0; j < 4; ++j) acc[i][j] = zz;
  int rr = lane & 15, cc = lane >> 4;
  int slot = (cc ^ ((rr >> 1) & 3)) * 8;
  for (int kt = 0; kt < K; kt += 32) {
    __syncthreads();
    *(u16x8*)&As[rs * 32 + cs * 8] = ra0;
    *(u16x8*)&As[(rs + 64) * 32 + cs * 8] = ra1;
    *(u16x8*)&Bs[rs * 32 + cs * 8] = rb0;
    *(u16x8*)&Bs[(rs + 64) * 32 + cs * 8] = rb1;
    if (kt + 32 < K) {
      ra0 = *(const u16x8*)(pa0 + kt + 32);
      ra1 = *(const u16x8*)(pa1 + kt + 32);
      rb0 = *(const u16x8*)(pb0 + kt + 32);
      rb1 = *(const u16x8*)(pb1 + kt + 32);
    }
    __syncthreads();
    f16x8 af[4], bfr[4];
#pragma unroll
    for (int f = 0; f < 4; ++f) {
      af[f]  = *(const f16x8*)&As[(wm * 64 + f * 16 + rr) * 32 + slot];
      bfr[f] = *(const f16x8*)&Bs[(wn * 64 + f * 16 + rr) * 32 + slot];
    }
#pragma unroll
    for (int fi = 0; fi < 4; ++fi)
#pragma unroll
      for (int fj = 0; fj < 4; ++fj)
        acc[fi][fj] = MFMA16F(bfr[fj], af[fi], acc[fi][fj]);  // swapped: C[n][m]
  }
#pragma unroll
  for (int fi = 0; fi < 4; ++fi) {
#pragma unroll
    for (int fj = 0; fj < 4; ++fj) {
      int m = m0 + wm * 64 + fi * 16 + rr;
      int n = n0 + wn * 64 + fj * 16 + cc * 4;
      ushort4 pk;
      pk.x = f2h(acc[fi][fj][0]); pk.y = f2h(acc[fi][fj][1]);
      pk.z = f2h(acc[fi][fj][2]); pk.w = f2h(acc[fi][fj][3]);
      *(ushort4*)&out[(size_t)m * 3072 + n] = pk;
    }
  }
}

// ---------------- V transpose + relu: vt[bh][64][2048] <- qkv v-part --------
__global__ __launch_bounds__(256) void vtrans(const unsigned short* __restrict__ qkv,
                                              unsigned short* __restrict__ vt) {
  __shared__ unsigned short tile[64][72];
  int q0 = blockIdx.x * 64;
  int bh = blockIdx.y;
  int b = bh >> 4, h = bh & 15;
  int t = threadIdx.x;
  int r = t >> 2, seg = t & 3;
  const unsigned short* src =
      qkv + (size_t)(b * 2048 + q0 + r) * 3072 + 2048 + h * 64 + seg * 16;
  *(u16x8*)&tile[r][seg * 16]     = *(const u16x8*)src;
  *(u16x8*)&tile[r][seg * 16 + 8] = *(const u16x8*)(src + 8);
  __syncthreads();
  int dh = t & 63, qs = t >> 6;
  unsigned short vals[16];
#pragma unroll
  for (int j = 0; j < 16; ++j) {
    unsigned short v = tile[qs * 16 + j][dh];
    vals[j] = (v & 0x8000) ? (unsigned short)0 : v;  // relu on f16 bits
  }
  unsigned short* dst = vt + (size_t)(bh * 64 + dh) * 2048 + q0 + qs * 16;
  *(u16x8*)&dst[0] = *(u16x8*)&vals[0];
  *(u16x8*)&dst[8] = *(u16x8*)&vals[8];
}

// ---------------- Attention v4: 512 threads (8 waves) per 16-query tile ------
// qkv [4096][3072] f16 (q pre-scaled), vt [32][64][2048] f16 (relu'd)
// O = ao [4096][1024] f16
#define DSF 2068  // f16 units per dots row (uint stride 1034 -> bank spread)
__global__ __launch_bounds__(512, 4) void attn4(
    const unsigned short* __restrict__ qkv, const unsigned short* __restrict__ Vt,
    unsigned short* __restrict__ O) {
  __shared__ unsigned short dotsH[16 * DSF];  // 66,176 B
  __shared__ float s_sh[16];
  __shared__ float out_sh[16 * 68];           //  4,352 B (total ~70.6 KB)
  int L = blockIdx.x;                 // 4096 linear; XCD-grouped: 4 bh per XCD
  int xcd = L & 7, idx = L >> 3;
  int bh = xcd * 4 + (idx >> 7);
  int q0 = (idx & 127) << 4;
  int b = bh >> 4, h = bh & 15;
  int t = threadIdx.x, lane = t & 63, wave = t >> 6;  // wave in 0..7
  int rr = lane & 15, cc = lane >> 4;

  const unsigned short* qbase = qkv + (size_t)(b * 2048) * 3072 + h * 64;
  const unsigned short* kbase = qkv + (size_t)(b * 2048) * 3072 + 1024 + h * 64;
  const unsigned short* Vh = Vt + (size_t)bh * 64 * 2048;

  f16x8 aq0 = *(const f16x8*)(qbase + (size_t)(q0 + rr) * 3072 + cc * 8);
  f16x8 aq1 = *(const f16x8*)(qbase + (size_t)(q0 + rr) * 3072 + 32 + cc * 8);

  for (int i = t; i < 16 * 68; i += 512) out_sh[i] = 0.f;

  // ---- phase 1: dots = Q K^T, 16 jb-tiles per wave ----
#pragma unroll 2
  for (int jb = wave; jb < 128; jb += 8) {
    const unsigned short* kp = kbase + (size_t)(jb * 16 + rr) * 3072 + cc * 8;
    f16x8 kb0 = *(const f16x8*)(kp);
    f16x8 kb1 = *(const f16x8*)(kp + 32);
    f32x4 acc = {0.f, 0.f, 0.f, 0.f};
    acc = MFMA16F(kb0, aq0, acc);
    acc = MFMA16F(kb1, aq1, acc);
    // C: col=rr -> query, row=cc*4+r -> key within 16-tile
    ushort4 pk;
    pk.x = f2h(acc[0]); pk.y = f2h(acc[1]); pk.z = f2h(acc[2]); pk.w = f2h(acc[3]);
    *(ushort4*)&dotsH[rr * DSF + jb * 16 + cc * 4] = pk;
  }
  __syncthreads();

  // ---- phase 2: exact top-k threshold via ballot binary search, 2 rows/wave ----
  const int KTOP = 204;
#pragma unroll 1
  for (int rw = 0; rw < 2; ++rw) {
    int row = wave * 2 + rw;
    const unsigned int* rp = (const unsigned int*)(dotsH + row * DSF);
    unsigned int keys[32];
#pragma unroll
    for (int k = 0; k < 16; ++k) {
      unsigned int w = rp[lane + 64 * k];
      keys[2 * k]     = key16(w & 0xFFFFu);
      keys[2 * k + 1] = key16(w >> 16);
    }
    // wave max of keys (for softmax stability)
    unsigned int kmax = 0;
#pragma unroll
    for (int k = 0; k < 32; ++k) kmax = kmax > keys[k] ? kmax : keys[k];
#pragma unroll
    for (int off = 32; off > 0; off >>= 1) {
      unsigned int o = (unsigned int)__shfl_xor((int)kmax, off);
      kmax = kmax > o ? kmax : o;
    }
    // binary search: largest T with count(key >= T) >= KTOP (ties kept)
    unsigned int cur = 0;
#pragma unroll 1
    for (int bit = 15; bit >= 0; --bit) {
      unsigned int cand = cur | (1u << bit);
      int cnt = 0;
#pragma unroll
      for (int k = 0; k < 32; ++k)
        cnt += __popcll(__ballot(keys[k] >= cand));
      if (cnt >= KTOP) cur = cand;
    }
    unsigned int thrKey = cur;
    float vmax = h2f(inv_key16(kmax));
    float sum = 0.f;
    unsigned int* wp = (unsigned int*)(dotsH + row * DSF);
#pragma unroll
    for (int k = 0; k < 16; ++k) {
      unsigned int k0 = keys[2 * k], k1 = keys[2 * k + 1];
      float p0 = (k0 >= thrKey) ? __expf(h2f(inv_key16(k0)) - vmax) : 0.f;
      float p1 = (k1 >= thrKey) ? __expf(h2f(inv_key16(k1)) - vmax) : 0.f;
      sum += p0 + p1;
      wp[lane + 64 * k] = (unsigned int)f2h(p0) | ((unsigned int)f2h(p1) << 16);
    }
    sum = wred_sum(sum);
    if (lane == 0) s_sh[row] = sum;
  }
  __syncthreads();

  // ---- phase 3: out = P @ V; wave -> dh block (wave&3), js half (wave>>2) ----
  f32x4 accp = {0.f, 0.f, 0.f, 0.f};
  int db = wave & 3;
  int js0 = (wave >> 2) * 32;
  const unsigned short* vrow = Vh + (size_t)(db * 16 + rr) * 2048;
#pragma unroll 4
  for (int js = js0; js < js0 + 32; ++js) {
    const unsigned short* pp = &dotsH[rr * DSF + js * 32 + cc * 8];
    uint2 lo = *(const uint2*)pp;
    uint2 hi = *(const uint2*)(pp + 4);
    uint4 tmp; tmp.x = lo.x; tmp.y = lo.y; tmp.z = hi.x; tmp.w = hi.y;
    f16x8 pa = __builtin_bit_cast(f16x8, tmp);
    f16x8 vb = *(const f16x8*)(vrow + js * 32 + cc * 8);
    accp = MFMA16F(pa, vb, accp);
  }
  // C: row=cc*4+r -> query, col=rr -> dh within block; combine wave pairs in LDS
#pragma unroll
  for (int r = 0; r < 4; ++r) {
    int q = cc * 4 + r;
    atomicAdd(&out_sh[q * 68 + db * 16 + rr], accp[r]);
  }
  __syncthreads();

  for (int i = t; i < 1024; i += 512) {
    int q = i >> 6, d = i & 63;
    float v = out_sh[q * 68 + d] / s_sh[q];
    O[(size_t)(b * 2048 + q0 + q) * 1024 + h * 64 + d] = f2h(v);
  }
}

// ---------------- GEMM2: out = ao @ Wout^T + bias (f32 out, f32x4 stores) ----
__global__ __launch_bounds__(256, 2) void gemm_out(
    const unsigned short* __restrict__ A, const unsigned short* __restrict__ W,
    const float* __restrict__ bias, float* __restrict__ out) {
  const int K = 1024;
  __shared__ unsigned short As[128 * 32];
  __shared__ unsigned short Bs[128 * 32];
  int t = threadIdx.x;
  int m0 = blockIdx.y * 128, n0 = blockIdx.x * 128;
  int lane = t & 63, wave = t >> 6;
  int wm = wave >> 1, wn = wave & 1;
  int rs = t >> 2, cs = t & 3;
  int cl = cs ^ ((rs >> 1) & 3);
  const unsigned short* pa0 = A + (size_t)(m0 + rs) * K + cl * 8;
  const unsigned short* pa1 = A + (size_t)(m0 + rs + 64) * K + cl * 8;
  const unsigned short* pb0 = W + (size_t)(n0 + rs) * K + cl * 8;
  const unsigned short* pb1 = W + (size_t)(n0 + rs + 64) * K + cl * 8;
  u16x8 ra0 = *(const u16x8*)pa0;
  u16x8 ra1 = *(const u16x8*)pa1;
  u16x8 rb0 = *(const u16x8*)pb0;
  u16x8 rb1 = *(const u16x8*)pb1;
  f32x4 zz = {0.f, 0.f, 0.f, 0.f};
  f32x4 acc[4][4];
#pragma unroll
  for (int i = 0; i < 4; ++i)
#pragma unroll
    for (int j = 0; j < 4; ++j) acc[i][j] = zz;
  int rr = lane & 15, cc = lane >> 4;
  int slot = (cc ^ ((rr >> 1) & 3)) * 8;
  for (int kt = 0; kt < K; kt += 32) {
    __syncthreads();
    *(u16x8*)&As[rs * 32 + cs * 8] = ra0;
    *(u16x8*)&As[(rs + 64) * 32 + cs * 8] = ra1;
    *(u16x8*)&Bs[rs * 32 + cs * 8] = rb0;
    *(u16x8*)&Bs[(rs + 64) * 32 + cs * 8] = rb1;
    if (kt + 32 < K) {
      ra0 = *(const u16x8*)(pa0 + kt + 32);
      ra1 = *(const u16x8*)(pa1 + kt + 32);
      rb0 = *(const u16x8*)(pb0 + kt + 32);
      rb1 = *(const u16x8*)(pb1 + kt + 32);
    }
    __syncthreads();
    f16x8 af[4], bfr[4];
#pragma unroll
    for (int f = 0; f < 4; ++f) {
      af[f]  = *(const f16x8*)&As[(wm * 64 + f * 16 + rr) * 32 + slot];
      bfr[f] = *(const f16x8*)&Bs[(wn * 64 + f * 16 + rr) * 32 + slot];
    }
#pragma unroll
    for (int fi = 0; fi < 4; ++fi)
#pragma unroll
      for (int fj = 0; fj < 4; ++fj)
        acc[fi][fj] = MFMA16F(bfr[fj], af[fi], acc[fi][fj]);  // swapped
  }
#pragma unroll
  for (int fi = 0; fi < 4; ++fi) {
#pragma unroll
    for (int fj = 0; fj < 4; ++fj) {
      int m = m0 + wm * 64 + fi * 16 + rr;
      int n = n0 + wn * 64 + fj * 16 + cc * 4;
      f32x4 bv = *(const f32x4*)&bias[n];
      f32x4 o = acc[fi][fj] + bv;
      *(f32x4*)&out[(size_t)m * 1024 + n] = o;
    }
  }
}

// ---------------------------------------------------------------------------
extern "C" void kernel_launch(void* const* d_in, const int* in_sizes, int n_in,
                              void* d_out, int out_size, void* d_ws,
                              size_t ws_size, hipStream_t stream) {
  (void)in_sizes; (void)n_in; (void)out_size; (void)ws_size;
  const float* x    = (const float*)d_in[0];
  const float* Wqkv = (const float*)d_in[1];
  const float* Wout = (const float*)d_in[2];
  const float* bout = (const float*)d_in[3];
  float* out = (float*)d_out;

  char* ws = (char*)d_ws;
  unsigned short* x_h  = (unsigned short*)(ws);              // 8 MB; reused as ao
  unsigned short* ao   = (unsigned short*)(ws);
  unsigned short* wq_h = (unsigned short*)(ws + 8388608);    // 6 MB; reused as vt
  unsigned short* vt   = (unsigned short*)(ws + 8388608);    // 8 MB
  unsigned short* wo_h = (unsigned short*)(ws + 16777216);   // 2 MB
  unsigned short* qkv  = (unsigned short*)(ws + 18874368);   // 24 MB (end ~44 MB)

  cast_f32_f16<<<1024, 256, 0, stream>>>(x, x_h, 1048576, 0);
  cast_f32_f16<<<768, 256, 0, stream>>>(Wqkv, wq_h, 786432, 262144);
  cast_f32_f16<<<256, 256, 0, stream>>>(Wout, wo_h, 262144, 0);
  gemm_qkv<<<dim3(24, 32), 256, 0, stream>>>(x_h, wq_h, qkv);
  vtrans<<<dim3(32, 32), 256, 0, stream>>>(qkv, vt);
  attn4<<<4096, 512, 0, stream>>>(qkv, vt, ao);
  gemm_out<<<dim3(8, 32), 256, 0, stream>>>(ao, wo_h, bout, out);
}

// Round 7
// 470.442 us; speedup vs baseline: 1.0280x; 1.0280x over previous
//
#include <hip/hip_runtime.h>

// ---------------------------------------------------------------------------
// SparseAttention v5: all-f16 MFMA pipeline.
// x @ Wqkv^T -> top-k(204/2048) masked softmax attn -> @ Wout^T
// b=2 n=2048 d=1024 h=16 dh=64, scale=1/32 (folded into Wqkv cast), k_top=204.
// attn: 16 queries/WG, 512 threads (8 waves). Dots tile f16 in LDS (16B-
// aligned rows, b128 access); top-k threshold via ballot binary search with
// the wave's TWO rows interleaved (2x ILP); K/V register prefetch in the
// MFMA phases.
// ---------------------------------------------------------------------------

using f16x8 = __attribute__((ext_vector_type(8))) _Float16;
using u16x8 = __attribute__((ext_vector_type(8))) unsigned short;
using f32x4 = __attribute__((ext_vector_type(4))) float;

#define MFMA16F(a, b, c) __builtin_amdgcn_mfma_f32_16x16x32_f16(a, b, c, 0, 0, 0)

__device__ __forceinline__ unsigned short f2h(float f) {
  return __builtin_bit_cast(unsigned short, (_Float16)f);
}
__device__ __forceinline__ float h2f(unsigned int u) {
  return (float)__builtin_bit_cast(_Float16, (unsigned short)u);
}
// monotone f16-bits -> u16 key (larger key == larger value)
__device__ __forceinline__ unsigned int key16(unsigned int u) {
  return (u & 0x8000u) ? (~u & 0xFFFFu) : (u | 0x8000u);
}
__device__ __forceinline__ unsigned int inv_key16(unsigned int k) {
  return (k & 0x8000u) ? (k & 0x7FFFu) : (~k & 0xFFFFu);
}
__device__ __forceinline__ float wred_sum(float v) {
#pragma unroll
  for (int off = 32; off > 0; off >>= 1) v += __shfl_xor(v, off);
  return v;
}

// ---------------- cast f32 -> f16 (x4), optional 1/32 scale for first scaleN4 ----
__global__ void cast_f32_f16(const float* __restrict__ s,
                             unsigned short* __restrict__ d, int n4, int scaleN4) {
  int i = blockIdx.x * blockDim.x + threadIdx.x;
  int stride = gridDim.x * blockDim.x;
  for (; i < n4; i += stride) {
    float4 v = ((const float4*)s)[i];
    float sc = (i < scaleN4) ? 0.03125f : 1.0f;
    ushort4 o;
    o.x = f2h(v.x * sc); o.y = f2h(v.y * sc); o.z = f2h(v.z * sc); o.w = f2h(v.w * sc);
    ((ushort4*)d)[i] = o;
  }
}

// ---------------- GEMM1: qkv[4096][3072] = x @ Wqkv^T (f16, coalesced) -------
__global__ __launch_bounds__(256, 2) void gemm_qkv(
    const unsigned short* __restrict__ A, const unsigned short* __restrict__ W,
    unsigned short* __restrict__ out) {
  const int K = 1024;
  __shared__ unsigned short As[128 * 32];
  __shared__ unsigned short Bs[128 * 32];
  int t = threadIdx.x;
  int m0 = blockIdx.y * 128, n0 = blockIdx.x * 128;
  int lane = t & 63, wave = t >> 6;
  int wm = wave >> 1, wn = wave & 1;
  int rs = t >> 2, cs = t & 3;
  int cl = cs ^ ((rs >> 1) & 3);
  const unsigned short* pa0 = A + (size_t)(m0 + rs) * K + cl * 8;
  const unsigned short* pa1 = A + (size_t)(m0 + rs + 64) * K + cl * 8;
  const unsigned short* pb0 = W + (size_t)(n0 + rs) * K + cl * 8;
  const unsigned short* pb1 = W + (size_t)(n0 + rs + 64) * K + cl * 8;
  u16x8 ra0 = *(const u16x8*)pa0;
  u16x8 ra1 = *(const u16x8*)pa1;
  u16x8 rb0 = *(const u16x8*)pb0;
  u16x8 rb1 = *(const u16x8*)pb1;
  f32x4 zz = {0.f, 0.f, 0.f, 0.f};
  f32x4 acc[4][4];
#pragma unroll
  for (int i = 0; i < 4; ++i)
#pragma unroll
    for (int j = 0; j < 4; ++j) acc[i][j] = zz;
  int rr = lane & 15, cc = lane >> 4;
  int slot = (cc ^ ((rr >> 1) & 3)) * 8;
  for (int kt = 0; kt < K; kt += 32) {
    __syncthreads();
    *(u16x8*)&As[rs * 32 + cs * 8] = ra0;
    *(u16x8*)&As[(rs + 64) * 32 + cs * 8] = ra1;
    *(u16x8*)&Bs[rs * 32 + cs * 8] = rb0;
    *(u16x8*)&Bs[(rs + 64) * 32 + cs * 8] = rb1;
    if (kt + 32 < K) {
      ra0 = *(const u16x8*)(pa0 + kt + 32);
      ra1 = *(const u16x8*)(pa1 + kt + 32);
      rb0 = *(const u16x8*)(pb0 + kt + 32);
      rb1 = *(const u16x8*)(pb1 + kt + 32);
    }
    __syncthreads();
    f16x8 af[4], bfr[4];
#pragma unroll
    for (int f = 0; f < 4; ++f) {
      af[f]  = *(const f16x8*)&As[(wm * 64 + f * 16 + rr) * 32 + slot];
      bfr[f] = *(const f16x8*)&Bs[(wn * 64 + f * 16 + rr) * 32 + slot];
    }
#pragma unroll
    for (int fi = 0; fi < 4; ++fi)
#pragma unroll
      for (int fj = 0; fj < 4; ++fj)
        acc[fi][fj] = MFMA16F(bfr[fj], af[fi], acc[fi][fj]);  // swapped: C[n][m]
  }
#pragma unroll
  for (int fi = 0; fi < 4; ++fi) {
#pragma unroll
    for (int fj = 0; fj < 4; ++fj) {
      int m = m0 + wm * 64 + fi * 16 + rr;
      int n = n0 + wn * 64 + fj * 16 + cc * 4;
      ushort4 pk;
      pk.x = f2h(acc[fi][fj][0]); pk.y = f2h(acc[fi][fj][1]);
      pk.z = f2h(acc[fi][fj][2]); pk.w = f2h(acc[fi][fj][3]);
      *(ushort4*)&out[(size_t)m * 3072 + n] = pk;
    }
  }
}

// ---------------- V transpose + relu: vt[bh][64][2048] <- qkv v-part --------
__global__ __launch_bounds__(256) void vtrans(const unsigned short* __restrict__ qkv,
                                              unsigned short* __restrict__ vt) {
  __shared__ unsigned short tile[64][72];
  int q0 = blockIdx.x * 64;
  int bh = blockIdx.y;
  int b = bh >> 4, h = bh & 15;
  int t = threadIdx.x;
  int r = t >> 2, seg = t & 3;
  const unsigned short* src =
      qkv + (size_t)(b * 2048 + q0 + r) * 3072 + 2048 + h * 64 + seg * 16;
  *(u16x8*)&tile[r][seg * 16]     = *(const u16x8*)src;
  *(u16x8*)&tile[r][seg * 16 + 8] = *(const u16x8*)(src + 8);
  __syncthreads();
  int dh = t & 63, qs = t >> 6;
  unsigned short vals[16];
#pragma unroll
  for (int j = 0; j < 16; ++j) {
    unsigned short v = tile[qs * 16 + j][dh];
    vals[j] = (v & 0x8000) ? (unsigned short)0 : v;  // relu on f16 bits
  }
  unsigned short* dst = vt + (size_t)(bh * 64 + dh) * 2048 + q0 + qs * 16;
  *(u16x8*)&dst[0] = *(u16x8*)&vals[0];
  *(u16x8*)&dst[8] = *(u16x8*)&vals[8];
}

// ---------------- Attention v5: 512 threads (8 waves) per 16-query tile ------
// qkv [4096][3072] f16 (q pre-scaled), vt [32][64][2048] f16 (relu'd)
// O = ao [4096][1024] f16
#define DSF 2072  // f16/row: 4144 B (16B-aligned rows; dword stride 1036 = 12 mod 32)
__global__ __launch_bounds__(512, 4) void attn5(
    const unsigned short* __restrict__ qkv, const unsigned short* __restrict__ Vt,
    unsigned short* __restrict__ O) {
  __shared__ unsigned short dotsH[16 * DSF];  // 66,304 B
  __shared__ float s_sh[16];
  __shared__ float out_sh[16 * 68];           //  4,352 B (total ~70.9 KB)
  int L = blockIdx.x;                 // 4096 linear; XCD-grouped: 4 bh per XCD
  int xcd = L & 7, idx = L >> 3;
  int bh = xcd * 4 + (idx >> 7);
  int q0 = (idx & 127) << 4;
  int b = bh >> 4, h = bh & 15;
  int t = threadIdx.x, lane = t & 63, wave = t >> 6;  // wave in 0..7
  int rr = lane & 15, cc = lane >> 4;

  const unsigned short* qbase = qkv + (size_t)(b * 2048) * 3072 + h * 64;
  const unsigned short* kbase = qkv + (size_t)(b * 2048) * 3072 + 1024 + h * 64;
  const unsigned short* Vh = Vt + (size_t)bh * 64 * 2048;

  f16x8 aq0 = *(const f16x8*)(qbase + (size_t)(q0 + rr) * 3072 + cc * 8);
  f16x8 aq1 = *(const f16x8*)(qbase + (size_t)(q0 + rr) * 3072 + 32 + cc * 8);

  for (int i = t; i < 16 * 68; i += 512) out_sh[i] = 0.f;

  // ---- phase 1: dots = Q K^T, 16 jb-tiles per wave, K prefetched 1 iter ahead ----
  {
    const unsigned short* kp = kbase + (size_t)(wave * 16 + rr) * 3072 + cc * 8;
    f16x8 kb0 = *(const f16x8*)(kp);
    f16x8 kb1 = *(const f16x8*)(kp + 32);
#pragma unroll 2
    for (int jb = wave; jb < 128; jb += 8) {
      f16x8 c0 = kb0, c1 = kb1;
      if (jb + 8 < 128) {
        const unsigned short* kn = kbase + (size_t)((jb + 8) * 16 + rr) * 3072 + cc * 8;
        kb0 = *(const f16x8*)(kn);
        kb1 = *(const f16x8*)(kn + 32);
      }
      f32x4 acc = {0.f, 0.f, 0.f, 0.f};
      acc = MFMA16F(c0, aq0, acc);
      acc = MFMA16F(c1, aq1, acc);
      // C: col=rr -> query, row=cc*4+r -> key within 16-tile
      ushort4 pk;
      pk.x = f2h(acc[0]); pk.y = f2h(acc[1]); pk.z = f2h(acc[2]); pk.w = f2h(acc[3]);
      *(ushort4*)&dotsH[rr * DSF + jb * 16 + cc * 4] = pk;
    }
  }
  __syncthreads();

  // ---- phase 2: exact top-k via ballot binary search, 2 rows INTERLEAVED ----
  const int KTOP = 204;
  {
    int rowA = wave * 2, rowB = rowA + 1;
    unsigned int* rpA = (unsigned int*)(dotsH + rowA * DSF);
    unsigned int* rpB = (unsigned int*)(dotsH + rowB * DSF);
    // lane's chunk: dwords lane*4 + j*256 (j=0..3) -> 32 keys/row, b128 loads
    uint4 rawA[4], rawB[4];
#pragma unroll
    for (int j = 0; j < 4; ++j) {
      rawA[j] = *(const uint4*)(rpA + lane * 4 + j * 256);
      rawB[j] = *(const uint4*)(rpB + lane * 4 + j * 256);
    }
    unsigned int kA[32], kB[32];
#pragma unroll
    for (int j = 0; j < 4; ++j) {
      const unsigned int* wA = (const unsigned int*)&rawA[j];
      const unsigned int* wB = (const unsigned int*)&rawB[j];
#pragma unroll
      for (int d = 0; d < 4; ++d) {
        kA[j * 8 + 2 * d]     = key16(wA[d] & 0xFFFFu);
        kA[j * 8 + 2 * d + 1] = key16(wA[d] >> 16);
        kB[j * 8 + 2 * d]     = key16(wB[d] & 0xFFFFu);
        kB[j * 8 + 2 * d + 1] = key16(wB[d] >> 16);
      }
    }
    unsigned int mA = 0, mB = 0;
#pragma unroll
    for (int k = 0; k < 32; ++k) {
      mA = mA > kA[k] ? mA : kA[k];
      mB = mB > kB[k] ? mB : kB[k];
    }
#pragma unroll
    for (int off = 32; off > 0; off >>= 1) {
      unsigned int oA = (unsigned int)__shfl_xor((int)mA, off);
      unsigned int oB = (unsigned int)__shfl_xor((int)mB, off);
      mA = mA > oA ? mA : oA;
      mB = mB > oB ? mB : oB;
    }
    // binary search both rows: largest T with count(key >= T) >= KTOP
    unsigned int curA = 0, curB = 0;
#pragma unroll 1
    for (int bit = 15; bit >= 0; --bit) {
      unsigned int candA = curA | (1u << bit);
      unsigned int candB = curB | (1u << bit);
      int cntA = 0, cntB = 0;
#pragma unroll
      for (int k = 0; k < 32; ++k) {
        cntA += __popcll(__ballot(kA[k] >= candA));
        cntB += __popcll(__ballot(kB[k] >= candB));
      }
      if (cntA >= KTOP) curA = candA;
      if (cntB >= KTOP) curB = candB;
    }
    float vmaxA = h2f(inv_key16(mA)), vmaxB = h2f(inv_key16(mB));
    float sumA = 0.f, sumB = 0.f;
#pragma unroll
    for (int j = 0; j < 4; ++j) {
      uint4 oA, oB;
#pragma unroll
      for (int d = 0; d < 4; ++d) {
        unsigned int a0 = kA[j * 8 + 2 * d], a1 = kA[j * 8 + 2 * d + 1];
        unsigned int b0 = kB[j * 8 + 2 * d], b1 = kB[j * 8 + 2 * d + 1];
        float pA0 = (a0 >= curA) ? __expf(h2f(inv_key16(a0)) - vmaxA) : 0.f;
        float pA1 = (a1 >= curA) ? __expf(h2f(inv_key16(a1)) - vmaxA) : 0.f;
        float pB0 = (b0 >= curB) ? __expf(h2f(inv_key16(b0)) - vmaxB) : 0.f;
        float pB1 = (b1 >= curB) ? __expf(h2f(inv_key16(b1)) - vmaxB) : 0.f;
        sumA += pA0 + pA1;
        sumB += pB0 + pB1;
        ((unsigned int*)&oA)[d] = (unsigned int)f2h(pA0) | ((unsigned int)f2h(pA1) << 16);
        ((unsigned int*)&oB)[d] = (unsigned int)f2h(pB0) | ((unsigned int)f2h(pB1) << 16);
      }
      *(uint4*)(rpA + lane * 4 + j * 256) = oA;
      *(uint4*)(rpB + lane * 4 + j * 256) = oB;
    }
    sumA = wred_sum(sumA);
    sumB = wred_sum(sumB);
    if (lane == 0) { s_sh[rowA] = sumA; s_sh[rowB] = sumB; }
  }
  __syncthreads();

  // ---- phase 3: out = P @ V; wave -> dh block (wave&3), js half (wave>>2) ----
  // V prefetched 1 iter ahead; P read as single b128 (rows 16B-aligned).
  {
    f32x4 accp = {0.f, 0.f, 0.f, 0.f};
    int db = wave & 3;
    int js0 = (wave >> 2) * 32;
    const unsigned short* vrow = Vh + (size_t)(db * 16 + rr) * 2048;
    f16x8 vb = *(const f16x8*)(vrow + js0 * 32 + cc * 8);
#pragma unroll 4
    for (int js = js0; js < js0 + 32; ++js) {
      f16x8 vcur = vb;
      if (js + 1 < js0 + 32) vb = *(const f16x8*)(vrow + (js + 1) * 32 + cc * 8);
      f16x8 pa = *(const f16x8*)&dotsH[rr * DSF + js * 32 + cc * 8];
      accp = MFMA16F(pa, vcur, accp);
    }
    // C: row=cc*4+r -> query, col=rr -> dh within block; combine pairs in LDS
#pragma unroll
    for (int r = 0; r < 4; ++r) {
      int q = cc * 4 + r;
      atomicAdd(&out_sh[q * 68 + db * 16 + rr], accp[r]);
    }
  }
  __syncthreads();

  for (int i = t; i < 1024; i += 512) {
    int q = i >> 6, d = i & 63;
    float v = out_sh[q * 68 + d] / s_sh[q];
    O[(size_t)(b * 2048 + q0 + q) * 1024 + h * 64 + d] = f2h(v);
  }
}

// ---------------- GEMM2: out = ao @ Wout^T + bias (f32 out, f32x4 stores) ----
__global__ __launch_bounds__(256, 2) void gemm_out(
    const unsigned short* __restrict__ A, const unsigned short* __restrict__ W,
    const float* __restrict__ bias, float* __restrict__ out) {
  const int K = 1024;
  __shared__ unsigned short As[128 * 32];
  __shared__ unsigned short Bs[128 * 32];
  int t = threadIdx.x;
  int m0 = blockIdx.y * 128, n0 = blockIdx.x * 128;
  int lane = t & 63, wave = t >> 6;
  int wm = wave >> 1, wn = wave & 1;
  int rs = t >> 2, cs = t & 3;
  int cl = cs ^ ((rs >> 1) & 3);
  const unsigned short* pa0 = A + (size_t)(m0 + rs) * K + cl * 8;
  const unsigned short* pa1 = A + (size_t)(m0 + rs + 64) * K + cl * 8;
  const unsigned short* pb0 = W + (size_t)(n0 + rs) * K + cl * 8;
  const unsigned short* pb1 = W + (size_t)(n0 + rs + 64) * K + cl * 8;
  u16x8 ra0 = *(const u16x8*)pa0;
  u16x8 ra1 = *(const u16x8*)pa1;
  u16x8 rb0 = *(const u16x8*)pb0;
  u16x8 rb1 = *(const u16x8*)pb1;
  f32x4 zz = {0.f, 0.f, 0.f, 0.f};
  f32x4 acc[4][4];
#pragma unroll
  for (int i = 0; i < 4; ++i)
#pragma unroll
    for (int j = 0; j < 4; ++j) acc[i][j] = zz;
  int rr = lane & 15, cc = lane >> 4;
  int slot = (cc ^ ((rr >> 1) & 3)) * 8;
  for (int kt = 0; kt < K; kt += 32) {
    __syncthreads();
    *(u16x8*)&As[rs * 32 + cs * 8] = ra0;
    *(u16x8*)&As[(rs + 64) * 32 + cs * 8] = ra1;
    *(u16x8*)&Bs[rs * 32 + cs * 8] = rb0;
    *(u16x8*)&Bs[(rs + 64) * 32 + cs * 8] = rb1;
    if (kt + 32 < K) {
      ra0 = *(const u16x8*)(pa0 + kt + 32);
      ra1 = *(const u16x8*)(pa1 + kt + 32);
      rb0 = *(const u16x8*)(pb0 + kt + 32);
      rb1 = *(const u16x8*)(pb1 + kt + 32);
    }
    __syncthreads();
    f16x8 af[4], bfr[4];
#pragma unroll
    for (int f = 0; f < 4; ++f) {
      af[f]  = *(const f16x8*)&As[(wm * 64 + f * 16 + rr) * 32 + slot];
      bfr[f] = *(const f16x8*)&Bs[(wn * 64 + f * 16 + rr) * 32 + slot];
    }
#pragma unroll
    for (int fi = 0; fi < 4; ++fi)
#pragma unroll
      for (int fj = 0; fj < 4; ++fj)
        acc[fi][fj] = MFMA16F(bfr[fj], af[fi], acc[fi][fj]);  // swapped
  }
#pragma unroll
  for (int fi = 0; fi < 4; ++fi) {
#pragma unroll
    for (int fj = 0; fj < 4; ++fj) {
      int m = m0 + wm * 64 + fi * 16 + rr;
      int n = n0 + wn * 64 + fj * 16 + cc * 4;
      f32x4 bv = *(const f32x4*)&bias[n];
      f32x4 o = acc[fi][fj] + bv;
      *(f32x4*)&out[(size_t)m * 1024 + n] = o;
    }
  }
}

// ---------------------------------------------------------------------------
extern "C" void kernel_launch(void* const* d_in, const int* in_sizes, int n_in,
                              void* d_out, int out_size, void* d_ws,
                              size_t ws_size, hipStream_t stream) {
  (void)in_sizes; (void)n_in; (void)out_size; (void)ws_size;
  const float* x    = (const float*)d_in[0];
  const float* Wqkv = (const float*)d_in[1];
  const float* Wout = (const float*)d_in[2];
  const float* bout = (const float*)d_in[3];
  float* out = (float*)d_out;

  char* ws = (char*)d_ws;
  unsigned short* x_h  = (unsigned short*)(ws);              // 8 MB; reused as ao
  unsigned short* ao   = (unsigned short*)(ws);
  unsigned short* wq_h = (unsigned short*)(ws + 8388608);    // 6 MB; reused as vt
  unsigned short* vt   = (unsigned short*)(ws + 8388608);    // 8 MB
  unsigned short* wo_h = (unsigned short*)(ws + 16777216);   // 2 MB
  unsigned short* qkv  = (unsigned short*)(ws + 18874368);   // 24 MB (end ~44 MB)

  cast_f32_f16<<<1024, 256, 0, stream>>>(x, x_h, 1048576, 0);
  cast_f32_f16<<<768, 256, 0, stream>>>(Wqkv, wq_h, 786432, 262144);
  cast_f32_f16<<<256, 256, 0, stream>>>(Wout, wo_h, 262144, 0);
  gemm_qkv<<<dim3(24, 32), 256, 0, stream>>>(x_h, wq_h, qkv);
  vtrans<<<dim3(32, 32), 256, 0, stream>>>(qkv, vt);
  attn5<<<4096, 512, 0, stream>>>(qkv, vt, ao);
  gemm_out<<<dim3(8, 32), 256, 0, stream>>>(ao, wo_h, bout, out);
}

// Round 11
// 452.926 us; speedup vs baseline: 1.0677x; 1.0387x over previous
//
#include <hip/hip_runtime.h>

// ---------------------------------------------------------------------------
// SparseAttention v6b: all-f16 MFMA pipeline (v6 + cvt_pkrtz type fix).
// x @ Wqkv^T -> top-k(204/2048) masked softmax attn -> @ Wout^T
// b=2 n=2048 d=1024 h=16 dh=64, scale=1/32 (folded into Wqkv cast), k_top=204.
// attn: 16 queries/WG, 512 threads (8 waves); dots f16 in LDS; top-k via
// ballot binary search in FLOAT domain (rows sequential, low reg pressure,
// no vmax -- softmax normalizes anyway); V transpose+relu fused into the
// QKV GEMM epilogue.
// ---------------------------------------------------------------------------

using f16x8 = __attribute__((ext_vector_type(8))) _Float16;
using u16x8 = __attribute__((ext_vector_type(8))) unsigned short;
using f32x4 = __attribute__((ext_vector_type(4))) float;

#define MFMA16F(a, b, c) __builtin_amdgcn_mfma_f32_16x16x32_f16(a, b, c, 0, 0, 0)

__device__ __forceinline__ unsigned short f2h(float f) {
  return __builtin_bit_cast(unsigned short, (_Float16)f);
}
__device__ __forceinline__ float h2f(unsigned int u) {
  return (float)__builtin_bit_cast(_Float16, (unsigned short)u);
}
// monotone u16 key -> f16 bits (inverse of key map)
__device__ __forceinline__ unsigned int inv_key16(unsigned int k) {
  return (k & 0x8000u) ? (k & 0x7FFFu) : (~k & 0xFFFFu);
}
// packed f32x2 -> f16x2 (RTZ) as a dword
__device__ __forceinline__ unsigned int pack_h2(float a, float b) {
  auto v = __builtin_amdgcn_cvt_pkrtz(a, b);  // __fp16 ext_vector(2)
  return __builtin_bit_cast(unsigned int, v);
}
__device__ __forceinline__ float wred_sum(float v) {
#pragma unroll
  for (int off = 32; off > 0; off >>= 1) v += __shfl_xor(v, off);
  return v;
}

// ---------------- cast f32 -> f16 (x4), optional 1/32 scale for first scaleN4 ----
__global__ void cast_f32_f16(const float* __restrict__ s,
                             unsigned short* __restrict__ d, int n4, int scaleN4) {
  int i = blockIdx.x * blockDim.x + threadIdx.x;
  int stride = gridDim.x * blockDim.x;
  for (; i < n4; i += stride) {
    float4 v = ((const float4*)s)[i];
    float sc = (i < scaleN4) ? 0.03125f : 1.0f;
    ushort4 o;
    o.x = f2h(v.x * sc); o.y = f2h(v.y * sc); o.z = f2h(v.z * sc); o.w = f2h(v.w * sc);
    ((ushort4*)d)[i] = o;
  }
}

// ---------------- GEMM1: x @ Wqkv^T -> q[bh][n][64], k[bh][n][64], vt[bh][64][n] ----
__global__ __launch_bounds__(256, 2) void gemm_qkv(
    const unsigned short* __restrict__ A, const unsigned short* __restrict__ W,
    unsigned short* __restrict__ qo, unsigned short* __restrict__ ko,
    unsigned short* __restrict__ vto) {
  const int K = 1024;
  __shared__ unsigned short As[128 * 32];
  __shared__ unsigned short Bs[128 * 32];
  int t = threadIdx.x;
  int m0 = blockIdx.y * 128, n0 = blockIdx.x * 128;
  int lane = t & 63, wave = t >> 6;
  int wm = wave >> 1, wn = wave & 1;
  int rs = t >> 2, cs = t & 3;
  int cl = cs ^ ((rs >> 1) & 3);
  const unsigned short* pa0 = A + (size_t)(m0 + rs) * K + cl * 8;
  const unsigned short* pa1 = A + (size_t)(m0 + rs + 64) * K + cl * 8;
  const unsigned short* pb0 = W + (size_t)(n0 + rs) * K + cl * 8;
  const unsigned short* pb1 = W + (size_t)(n0 + rs + 64) * K + cl * 8;
  u16x8 ra0 = *(const u16x8*)pa0;
  u16x8 ra1 = *(const u16x8*)pa1;
  u16x8 rb0 = *(const u16x8*)pb0;
  u16x8 rb1 = *(const u16x8*)pb1;
  f32x4 zz = {0.f, 0.f, 0.f, 0.f};
  f32x4 acc[4][4];
#pragma unroll
  for (int i = 0; i < 4; ++i)
#pragma unroll
    for (int j = 0; j < 4; ++j) acc[i][j] = zz;
  int rr = lane & 15, cc = lane >> 4;
  int slot = (cc ^ ((rr >> 1) & 3)) * 8;
  for (int kt = 0; kt < K; kt += 32) {
    __syncthreads();
    *(u16x8*)&As[rs * 32 + cs * 8] = ra0;
    *(u16x8*)&As[(rs + 64) * 32 + cs * 8] = ra1;
    *(u16x8*)&Bs[rs * 32 + cs * 8] = rb0;
    *(u16x8*)&Bs[(rs + 64) * 32 + cs * 8] = rb1;
    if (kt + 32 < K) {
      ra0 = *(const u16x8*)(pa0 + kt + 32);
      ra1 = *(const u16x8*)(pa1 + kt + 32);
      rb0 = *(const u16x8*)(pb0 + kt + 32);
      rb1 = *(const u16x8*)(pb1 + kt + 32);
    }
    __syncthreads();
    f16x8 af[4], bfr[4];
#pragma unroll
    for (int f = 0; f < 4; ++f) {
      af[f]  = *(const f16x8*)&As[(wm * 64 + f * 16 + rr) * 32 + slot];
      bfr[f] = *(const f16x8*)&Bs[(wn * 64 + f * 16 + rr) * 32 + slot];
    }
#pragma unroll
    for (int fi = 0; fi < 4; ++fi)
#pragma unroll
      for (int fj = 0; fj < 4; ++fj)
        acc[fi][fj] = MFMA16F(bfr[fj], af[fi], acc[fi][fj]);  // swapped: C[n][m]
  }
  int sub = n0 >> 10;  // 0=q 1=k 2=v (128-tile never crosses a boundary)
#pragma unroll
  for (int fi = 0; fi < 4; ++fi) {
#pragma unroll
    for (int fj = 0; fj < 4; ++fj) {
      int m = m0 + wm * 64 + fi * 16 + rr;          // sequence index
      int nb = n0 + wn * 64 + fj * 16 + cc * 4;     // channel base (4-aligned)
      int b = m >> 11, nq = m & 2047;
      int ch = nb & 1023, hh = ch >> 6, dh0 = ch & 63;
      size_t bh = (size_t)(b * 16 + hh);
      if (sub < 2) {
        ushort4 pk;
        pk.x = f2h(acc[fi][fj][0]); pk.y = f2h(acc[fi][fj][1]);
        pk.z = f2h(acc[fi][fj][2]); pk.w = f2h(acc[fi][fj][3]);
        unsigned short* dst = (sub == 0 ? qo : ko) + (bh * 2048 + nq) * 64 + dh0;
        *(ushort4*)dst = pk;
      } else {
#pragma unroll
        for (int r = 0; r < 4; ++r) {
          float v = fmaxf(acc[fi][fj][r], 0.f);  // relu
          vto[(bh * 64 + (dh0 + r)) * 2048 + nq] = f2h(v);
        }
      }
    }
  }
}

// ---------------- Attention v6: 512 threads (8 waves) per 16-query tile ------
// q,k [32][2048][64] f16 (q pre-scaled), vt [32][64][2048] f16 (relu'd)
// O = ao [4096][1024] f16
#define DSF 2072  // f16/row: 4144 B (16B-aligned rows)
__global__ __launch_bounds__(512, 4) void attn6(
    const unsigned short* __restrict__ Q, const unsigned short* __restrict__ Kt,
    const unsigned short* __restrict__ Vt, unsigned short* __restrict__ O) {
  __shared__ unsigned short dotsH[16 * DSF];  // 66,304 B
  __shared__ float s_sh[16];
  __shared__ float out_sh[16 * 68];           //  4,352 B
  int L = blockIdx.x;                 // 4096 linear; XCD-grouped: 4 bh per XCD
  int xcd = L & 7, idx = L >> 3;
  int bh = xcd * 4 + (idx >> 7);
  int q0 = (idx & 127) << 4;
  int b = bh >> 4, h = bh & 15;
  int t = threadIdx.x, lane = t & 63, wave = t >> 6;  // wave in 0..7
  int rr = lane & 15, cc = lane >> 4;

  const unsigned short* Qh = Q + (size_t)bh * 2048 * 64;
  const unsigned short* Kh = Kt + (size_t)bh * 2048 * 64;
  const unsigned short* Vh = Vt + (size_t)bh * 64 * 2048;

  f16x8 aq0 = *(const f16x8*)(Qh + (size_t)(q0 + rr) * 64 + cc * 8);
  f16x8 aq1 = *(const f16x8*)(Qh + (size_t)(q0 + rr) * 64 + 32 + cc * 8);

  for (int i = t; i < 16 * 68; i += 512) out_sh[i] = 0.f;

  // ---- phase 1: dots = Q K^T, 16 jb-tiles per wave, K prefetched 1 iter ahead ----
  {
    const unsigned short* kp = Kh + (size_t)(wave * 16 + rr) * 64 + cc * 8;
    f16x8 kb0 = *(const f16x8*)(kp);
    f16x8 kb1 = *(const f16x8*)(kp + 32);
#pragma unroll 2
    for (int jb = wave; jb < 128; jb += 8) {
      f16x8 c0 = kb0, c1 = kb1;
      if (jb + 8 < 128) {
        const unsigned short* kn = Kh + (size_t)((jb + 8) * 16 + rr) * 64 + cc * 8;
        kb0 = *(const f16x8*)(kn);
        kb1 = *(const f16x8*)(kn + 32);
      }
      f32x4 acc = {0.f, 0.f, 0.f, 0.f};
      acc = MFMA16F(c0, aq0, acc);
      acc = MFMA16F(c1, aq1, acc);
      // C: col=rr -> query, row=cc*4+r -> key within 16-tile
      ushort4 pk;
      pk.x = f2h(acc[0]); pk.y = f2h(acc[1]); pk.z = f2h(acc[2]); pk.w = f2h(acc[3]);
      *(ushort4*)&dotsH[rr * DSF + jb * 16 + cc * 4] = pk;
    }
  }
  __syncthreads();

  // ---- phase 2: exact top-k via ballot binary search (float domain), 2 rows seq ----
  const int KTOP = 204;
#pragma unroll 1
  for (int rw = 0; rw < 2; ++rw) {
    int row = wave * 2 + rw;
    unsigned int* rp = (unsigned int*)(dotsH + row * DSF);
    uint4 raw[4];
#pragma unroll
    for (int j = 0; j < 4; ++j) raw[j] = *(const uint4*)(rp + lane * 4 + j * 256);
    float vals[32];
#pragma unroll
    for (int j = 0; j < 4; ++j) {
      const unsigned int* w = (const unsigned int*)&raw[j];
#pragma unroll
      for (int d = 0; d < 4; ++d) {
        vals[j * 8 + 2 * d]     = h2f(w[d] & 0xFFFFu);
        vals[j * 8 + 2 * d + 1] = h2f(w[d] >> 16);
      }
    }
    // binary search in key space, compares in float domain:
    // largest T with count(val >= T) >= KTOP (ties kept)
    unsigned int cur = 0;
#pragma unroll 1
    for (int bit = 15; bit >= 0; --bit) {
      unsigned int cand = cur | (1u << bit);
      float cf = h2f(inv_key16(cand));
      int cnt = 0;
#pragma unroll
      for (int k = 0; k < 32; ++k)
        cnt += __popcll(__ballot(vals[k] >= cf));
      if (cnt >= KTOP) cur = cand;
    }
    float thrF = h2f(inv_key16(cur));
    // p = exp(s) (no max subtraction -- softmax normalizes; |s| ~ O(1))
    float sum = 0.f;
#pragma unroll
    for (int j = 0; j < 4; ++j) {
      uint4 o;
#pragma unroll
      for (int d = 0; d < 4; ++d) {
        float v0 = vals[j * 8 + 2 * d], v1 = vals[j * 8 + 2 * d + 1];
        float p0 = (v0 >= thrF) ? __expf(v0) : 0.f;
        float p1 = (v1 >= thrF) ? __expf(v1) : 0.f;
        sum += p0 + p1;
        ((unsigned int*)&o)[d] = pack_h2(p0, p1);
      }
      *(uint4*)(rp + lane * 4 + j * 256) = o;
    }
    sum = wred_sum(sum);
    if (lane == 0) s_sh[row] = sum;
  }
  __syncthreads();

  // ---- phase 3: out = P @ V; wave -> dh block (wave&3), js half (wave>>2) ----
  {
    f32x4 accp = {0.f, 0.f, 0.f, 0.f};
    int db = wave & 3;
    int js0 = (wave >> 2) * 32;
    const unsigned short* vrow = Vh + (size_t)(db * 16 + rr) * 2048;
    f16x8 vb = *(const f16x8*)(vrow + js0 * 32 + cc * 8);
#pragma unroll 4
    for (int js = js0; js < js0 + 32; ++js) {
      f16x8 vcur = vb;
      if (js + 1 < js0 + 32) vb = *(const f16x8*)(vrow + (js + 1) * 32 + cc * 8);
      f16x8 pa = *(const f16x8*)&dotsH[rr * DSF + js * 32 + cc * 8];
      accp = MFMA16F(pa, vcur, accp);
    }
    // C: row=cc*4+r -> query, col=rr -> dh within block; combine halves in LDS
#pragma unroll
    for (int r = 0; r < 4; ++r) {
      int q = cc * 4 + r;
      atomicAdd(&out_sh[q * 68 + db * 16 + rr], accp[r]);
    }
  }
  __syncthreads();

  for (int i = t; i < 1024; i += 512) {
    int q = i >> 6, d = i & 63;
    float v = out_sh[q * 68 + d] / s_sh[q];
    O[(size_t)(b * 2048 + q0 + q) * 1024 + h * 64 + d] = f2h(v);
  }
}

// ---------------- GEMM2: out = ao @ Wout^T + bias (f32 out, f32x4 stores) ----
__global__ __launch_bounds__(256, 2) void gemm_out(
    const unsigned short* __restrict__ A, const unsigned short* __restrict__ W,
    const float* __restrict__ bias, float* __restrict__ out) {
  const int K = 1024;
  __shared__ unsigned short As[128 * 32];
  __shared__ unsigned short Bs[128 * 32];
  int t = threadIdx.x;
  int m0 = blockIdx.y * 128, n0 = blockIdx.x * 128;
  int lane = t & 63, wave = t >> 6;
  int wm = wave >> 1, wn = wave & 1;
  int rs = t >> 2, cs = t & 3;
  int cl = cs ^ ((rs >> 1) & 3);
  const unsigned short* pa0 = A + (size_t)(m0 + rs) * K + cl * 8;
  const unsigned short* pa1 = A + (size_t)(m0 + rs + 64) * K + cl * 8;
  const unsigned short* pb0 = W + (size_t)(n0 + rs) * K + cl * 8;
  const unsigned short* pb1 = W + (size_t)(n0 + rs + 64) * K + cl * 8;
  u16x8 ra0 = *(const u16x8*)pa0;
  u16x8 ra1 = *(const u16x8*)pa1;
  u16x8 rb0 = *(const u16x8*)pb0;
  u16x8 rb1 = *(const u16x8*)pb1;
  f32x4 zz = {0.f, 0.f, 0.f, 0.f};
  f32x4 acc[4][4];
#pragma unroll
  for (int i = 0; i < 4; ++i)
#pragma unroll
    for (int j = 0; j < 4; ++j) acc[i][j] = zz;
  int rr = lane & 15, cc = lane >> 4;
  int slot = (cc ^ ((rr >> 1) & 3)) * 8;
  for (int kt = 0; kt < K; kt += 32) {
    __syncthreads();
    *(u16x8*)&As[rs * 32 + cs * 8] = ra0;
    *(u16x8*)&As[(rs + 64) * 32 + cs * 8] = ra1;
    *(u16x8*)&Bs[rs * 32 + cs * 8] = rb0;
    *(u16x8*)&Bs[(rs + 64) * 32 + cs * 8] = rb1;
    if (kt + 32 < K) {
      ra0 = *(const u16x8*)(pa0 + kt + 32);
      ra1 = *(const u16x8*)(pa1 + kt + 32);
      rb0 = *(const u16x8*)(pb0 + kt + 32);
      rb1 = *(const u16x8*)(pb1 + kt + 32);
    }
    __syncthreads();
    f16x8 af[4], bfr[4];
#pragma unroll
    for (int f = 0; f < 4; ++f) {
      af[f]  = *(const f16x8*)&As[(wm * 64 + f * 16 + rr) * 32 + slot];
      bfr[f] = *(const f16x8*)&Bs[(wn * 64 + f * 16 + rr) * 32 + slot];
    }
#pragma unroll
    for (int fi = 0; fi < 4; ++fi)
#pragma unroll
      for (int fj = 0; fj < 4; ++fj)
        acc[fi][fj] = MFMA16F(bfr[fj], af[fi], acc[fi][fj]);  // swapped
  }
#pragma unroll
  for (int fi = 0; fi < 4; ++fi) {
#pragma unroll
    for (int fj = 0; fj < 4; ++fj) {
      int m = m0 + wm * 64 + fi * 16 + rr;
      int n = n0 + wn * 64 + fj * 16 + cc * 4;
      f32x4 bv = *(const f32x4*)&bias[n];
      f32x4 o = acc[fi][fj] + bv;
      *(f32x4*)&out[(size_t)m * 1024 + n] = o;
    }
  }
}

// ---------------------------------------------------------------------------
extern "C" void kernel_launch(void* const* d_in, const int* in_sizes, int n_in,
                              void* d_out, int out_size, void* d_ws,
                              size_t ws_size, hipStream_t stream) {
  (void)in_sizes; (void)n_in; (void)out_size; (void)ws_size;
  const float* x    = (const float*)d_in[0];
  const float* Wqkv = (const float*)d_in[1];
  const float* Wout = (const float*)d_in[2];
  const float* bout = (const float*)d_in[3];
  float* out = (float*)d_out;

  char* ws = (char*)d_ws;
  unsigned short* x_h  = (unsigned short*)(ws);              // 8 MB; reused as ao
  unsigned short* ao   = (unsigned short*)(ws);
  unsigned short* wq_h = (unsigned short*)(ws + 8388608);    // 6 MB
  unsigned short* wo_h = (unsigned short*)(ws + 14680064);   // 2 MB
  unsigned short* q_h  = (unsigned short*)(ws + 16777216);   // 8 MB
  unsigned short* k_h  = (unsigned short*)(ws + 25165824);   // 8 MB
  unsigned short* vt   = (unsigned short*)(ws + 33554432);   // 8 MB (end 40 MB)

  cast_f32_f16<<<1024, 256, 0, stream>>>(x, x_h, 1048576, 0);
  cast_f32_f16<<<768, 256, 0, stream>>>(Wqkv, wq_h, 786432, 262144);
  cast_f32_f16<<<256, 256, 0, stream>>>(Wout, wo_h, 262144, 0);
  gemm_qkv<<<dim3(24, 32), 256, 0, stream>>>(x_h, wq_h, q_h, k_h, vt);
  attn6<<<4096, 512, 0, stream>>>(q_h, k_h, vt, ao);
  gemm_out<<<dim3(8, 32), 256, 0, stream>>>(ao, wo_h, bout, out);
}